// Round 6
// baseline (498.867 us; speedup 1.0000x reference)
//
#include <hip/hip_runtime.h>
#include <cstdint>

#define T_LEN 4096
#define BATCH 4
#define DIM   1024
#define NH    8
#define HDIM  128
#define ROWS  16384   // BATCH * T_LEN

typedef __bf16 bf16x8 __attribute__((ext_vector_type(8)));
typedef float  f32x4  __attribute__((ext_vector_type(4)));

__device__ __forceinline__ unsigned short f2bf(float f) {
  union { float f; unsigned u; } a; a.f = f;
  unsigned u = a.u;
  u += 0x7fff + ((u >> 16) & 1);   // RNE
  return (unsigned short)(u >> 16);
}
__device__ __forceinline__ float bf2f(unsigned short h) {
  union { unsigned u; float f; } a; a.u = ((unsigned)h) << 16;
  return a.f;
}

__device__ __forceinline__ void gld_lds16(const unsigned short* g, unsigned short* l) {
  __builtin_amdgcn_global_load_lds(
      (const __attribute__((address_space(1))) unsigned int*)g,
      (__attribute__((address_space(3))) unsigned int*)l, 16, 0, 0);
}

// ---- LayerNorm (blocks 0..16383) + weight convert (blocks 16384..19455) + Zk/cnt zeroing ----
__global__ __launch_bounds__(256) void lnw_kernel(
    const float* __restrict__ x, const float* __restrict__ nw, const float* __restrict__ nb,
    const float* __restrict__ tw, const float* __restrict__ tb,
    unsigned short* __restrict__ xn, unsigned short* __restrict__ xtn,
    const float* __restrict__ Wq, const float* __restrict__ Wk, const float* __restrict__ Wv,
    unsigned short* __restrict__ wbf, float* __restrict__ Zk, int* __restrict__ cnt) {
  int tid = threadIdx.x;
  if (blockIdx.x >= ROWS) {
    int wb = blockIdx.x - ROWS;
    if (wb < 16) Zk[wb * 256 + tid] = 0.0f;           // zero Zk (4096 floats)
    if (wb == 16 && tid < 32) cnt[tid] = 0;           // zero att completion counters
    int i4 = wb * 256 + tid;
    int w = i4 >> 18;
    const float* src = (w == 0) ? Wq : (w == 1 ? Wk : Wv);
    float4 v = ((const float4*)src)[i4 & 262143];
    union { unsigned short u[4]; uint2 d; } o;
    o.u[0] = f2bf(v.x); o.u[1] = f2bf(v.y); o.u[2] = f2bf(v.z); o.u[3] = f2bf(v.w);
    ((uint2*)wbf)[i4] = o.d;
    return;
  }
  int row = blockIdx.x;               // t*B + b
  int t = row >> 2, b = row & 3;
  const float4 v = ((const float4*)(x + (size_t)row * DIM))[tid];
  float s  = v.x + v.y + v.z + v.w;
  float s2 = v.x*v.x + v.y*v.y + v.z*v.z + v.w*v.w;
#pragma unroll
  for (int o = 32; o; o >>= 1) { s += __shfl_xor(s, o); s2 += __shfl_xor(s2, o); }
  __shared__ float red[8];
  int wv = tid >> 6;
  if ((tid & 63) == 0) { red[wv] = s; red[4 + wv] = s2; }
  __syncthreads();
  s  = red[0] + red[1] + red[2] + red[3];
  s2 = red[4] + red[5] + red[6] + red[7];
  float mean = s * (1.0f / DIM);
  float var  = s2 * (1.0f / DIM) - mean * mean;
  float rstd = rsqrtf(var + 1e-5f);
  size_t orow = ((size_t)b * T_LEN + t) * DIM;
  int c0 = tid * 4;
  float xv[4] = {v.x, v.y, v.z, v.w};
  union { unsigned short u[4]; uint2 d; } o1, o2;
#pragma unroll
  for (int j = 0; j < 4; ++j) {
    int c = c0 + j;
    float xh = (xv[j] - mean) * rstd;
    o1.u[j] = f2bf(xh * nw[c] + nb[c]);
    o2.u[j] = f2bf(xh * tw[c] + tb[c]);
  }
  *(uint2*)(xn  + orow + c0) = o1.d;
  *(uint2*)(xtn + orow + c0) = o2.d;
}

// ---------------- K/V GEMM: BM=256 BN=128 BK=32, 8 waves, 48KB LDS, (512,4) no-spill ----------------
// zz==1: ksmT[b][c][t] = exp(k + bk) (transposed out) + fused Zk column-sum via atomics
// zz==2: vT[b][c][t]   = v + bv      (transposed out)
__global__ __launch_bounds__(512, 4) void kv_gemm(
    const unsigned short* __restrict__ xtn, const unsigned short* __restrict__ wbf,
    const float* __restrict__ bk, const float* __restrict__ bv,
    unsigned short* __restrict__ ko, unsigned short* __restrict__ vo,
    float* __restrict__ Zk) {
  int zz = blockIdx.z + 1;
  const unsigned short* W = wbf + (size_t)zz * DIM * DIM;
  const float* bias = (zz == 1) ? bk : bv;
  unsigned short* outp = (zz == 1) ? ko : vo;

  int m0 = blockIdx.x * 256;
  int n0 = blockIdx.y * 128;

  __shared__ __align__(16) unsigned short lds[24576];

  int tid = threadIdx.x;
  int wave = tid >> 6, lane = tid & 63;
  int wr = wave >> 1, wc = wave & 1;
  int wm = wr * 64, wn = wc * 64;
  int l16 = lane & 15, kq = lane >> 4;
  int rs = (kq ^ ((l16 >> 1) & 3)) * 8;     // conflict-free read slot (2 lanes/bank)

  int arow = tid >> 2;
  int achk = (tid & 3) ^ ((tid >> 3) & 3);
  const unsigned short* Ag = xtn + (size_t)(m0 + arow) * DIM + achk * 8;
  const unsigned short* Wg = W + (size_t)(n0 + arow) * DIM + achk * 8;

  f32x4 acc[4][4] = {};

  auto stage = [&](int tt, int sb) {
    int kt = tt * 32;
    gld_lds16(Ag + kt,                     lds + sb + wave * 512);
    gld_lds16(Ag + (size_t)128 * DIM + kt, lds + sb + 4096 + wave * 512);
    gld_lds16(Wg + kt,                     lds + sb + 8192 + wave * 512);
  };

  stage(0, 0);
  stage(1, 12288);

  for (int t = 0; t < 32; ++t) {
    int sb = (t & 1) ? 12288 : 0;
    const unsigned short* As = lds + sb;
    const unsigned short* Bs = lds + sb + 8192;

    if (t < 31) asm volatile("s_waitcnt vmcnt(3)" ::: "memory");
    else        asm volatile("s_waitcnt vmcnt(0)" ::: "memory");
    __builtin_amdgcn_sched_barrier(0);
    __builtin_amdgcn_s_barrier();
    __builtin_amdgcn_sched_barrier(0);

    bf16x8 fa[4], fb[4];
#pragma unroll
    for (int i = 0; i < 4; ++i) {
      fa[i] = *(const bf16x8*)(As + (wm + i * 16 + l16) * 32 + rs);
      fb[i] = *(const bf16x8*)(Bs + (wn + i * 16 + l16) * 32 + rs);
    }
#pragma unroll
    for (int i = 0; i < 4; ++i)
#pragma unroll
      for (int j = 0; j < 4; ++j)
        acc[i][j] = __builtin_amdgcn_mfma_f32_16x16x32_bf16(fa[i], fb[j], acc[i][j], 0, 0, 0);

    __builtin_amdgcn_sched_barrier(0);
    __builtin_amdgcn_s_barrier();
    __builtin_amdgcn_sched_barrier(0);
    if (t < 30) stage(t + 2, sb);
    __builtin_amdgcn_sched_barrier(0);
  }

  // bias
#pragma unroll
  for (int j = 0; j < 4; ++j) {
    float bc = bias[n0 + wn + j * 16 + l16];
#pragma unroll
    for (int i = 0; i < 4; ++i)
#pragma unroll
      for (int r = 0; r < 4; ++r) acc[i][j][r] += bc;
  }

  // transposed store: outp[b][col][t]; BM=256 never crosses a batch boundary
  int b = m0 >> 12;
  int tb = m0 & 4095;
  unsigned short* obase = outp + (size_t)b * DIM * T_LEN + tb;
  bool doExp = (zz == 1);
  float zs[4] = {0.0f, 0.0f, 0.0f, 0.0f};
#pragma unroll
  for (int j = 0; j < 4; ++j) {
    int col = n0 + wn + j * 16 + l16;
    unsigned short* cp = obase + (size_t)col * T_LEN;
#pragma unroll
    for (int i = 0; i < 4; ++i) {
      int t0 = wm + i * 16 + kq * 4;
      union { unsigned short u[4]; uint2 d; } o;
#pragma unroll
      for (int r = 0; r < 4; ++r) {
        float val = acc[i][j][r];
        if (doExp) { val = __expf(val); zs[j] += val; }
        o.u[r] = f2bf(val);
      }
      *(uint2*)(cp + t0) = o.d;
    }
  }
  if (doExp) {
#pragma unroll
    for (int j = 0; j < 4; ++j) {
      zs[j] += __shfl_xor(zs[j], 16);
      zs[j] += __shfl_xor(zs[j], 32);
      if (kq == 0) {
        int col = n0 + wn + j * 16 + l16;
        atomicAdd(Zk + b * DIM + col, zs[j]);
      }
    }
  }
}

// ---------------- att GEMM: 16 private split-K slabs + fused last-block reduction ----------------
// slab[kc][bh][l][d] = sum_{t in chunk kc} vT[l][t]*ksmT[d][t]; last finisher per bh
// sums 16 slabs, normalizes by Zk, writes attbf (device-scope fence + atomic counter, G16).
__global__ __launch_bounds__(256) void att_gemm(
    const unsigned short* __restrict__ vT, const unsigned short* __restrict__ ksmT,
    float* __restrict__ slabs, const float* __restrict__ Zk,
    unsigned short* __restrict__ attbf, int* __restrict__ cnt) {
  int kc = blockIdx.x;
  int bh = blockIdx.y;
  const unsigned short* Arow = vT   + (size_t)bh * HDIM * T_LEN;
  const unsigned short* Brow = ksmT + (size_t)bh * HDIM * T_LEN;
  __shared__ __align__(16) unsigned short As[128 * 64];
  __shared__ __align__(16) unsigned short Bs[128 * 64];
  int tid = threadIdx.x;
  int wave = tid >> 6, lane = tid & 63;
  int wm = (wave >> 1) * 64, wn = (wave & 1) * 64;
  int l16 = lane & 15, kq = lane >> 4;
  int swz = l16 & 7;
  int srow = tid >> 3;
  int skk = (((tid & 7) ^ ((tid >> 3) & 7)) * 8);
  const unsigned short* Ag = Arow + (size_t)srow * T_LEN + skk;
  const unsigned short* Bg = Brow + (size_t)srow * T_LEN + skk;
  unsigned short* Al = As + wave * 512;
  unsigned short* Bl = Bs + wave * 512;
  f32x4 acc[4][4] = {};
  int kbeg = kc * 256;
  for (int kt = kbeg; kt < kbeg + 256; kt += 64) {
#pragma unroll
    for (int p = 0; p < 4; ++p) {
      gld_lds16(Ag + (size_t)(p * 32) * T_LEN + kt, Al + p * 2048);
      gld_lds16(Bg + (size_t)(p * 32) * T_LEN + kt, Bl + p * 2048);
    }
    __syncthreads();
#pragma unroll
    for (int ks4 = 0; ks4 < 2; ++ks4) {
      int coff = (((kq + ks4 * 4) ^ swz) * 8);
      bf16x8 fa[4], fb[4];
#pragma unroll
      for (int i = 0; i < 4; ++i) {
        fa[i] = *(const bf16x8*)(As + (wm + i * 16 + l16) * 64 + coff);
        fb[i] = *(const bf16x8*)(Bs + (wn + i * 16 + l16) * 64 + coff);
      }
#pragma unroll
      for (int i = 0; i < 4; ++i)
#pragma unroll
        for (int j = 0; j < 4; ++j)
          acc[i][j] = __builtin_amdgcn_mfma_f32_16x16x32_bf16(fa[i], fb[j], acc[i][j], 0, 0, 0);
    }
    __syncthreads();
  }
  float* op = slabs + ((size_t)kc * 32 + bh) * 16384;
#pragma unroll
  for (int j = 0; j < 4; ++j) {
    int col = wn + j * 16 + l16;
#pragma unroll
    for (int i = 0; i < 4; ++i) {
      int rb = wm + i * 16 + kq * 4;
#pragma unroll
      for (int r = 0; r < 4; ++r)
        op[(size_t)(rb + r) * 128 + col] = acc[i][j][r];
    }
  }

  // completion signal: release fence, then one atomic per block
  __threadfence();
  __syncthreads();
  __shared__ int isLast;
  if (tid == 0) isLast = (atomicAdd(cnt + bh, 1) == 15) ? 1 : 0;
  __syncthreads();
  if (isLast) {
    __threadfence();   // acquire: see all 16 slabs
    int b = bh >> 3, h = bh & 7;
#pragma unroll 4
    for (int q = 0; q < 64; ++q) {
      int pos = q * 256 + tid;
      float s = 0.0f;
#pragma unroll
      for (int k = 0; k < 16; ++k) s += slabs[((size_t)k * 32 + bh) * 16384 + pos];
      float zv = Zk[b * DIM + h * HDIM + (pos & 127)];
      attbf[(size_t)bh * 16384 + pos] = f2bf(s / zv);
    }
  }
}

// ---------------- fused q GEMM + head-dim softmax + y GEMM ----------------
// Epilogue keeps acc DEAD before the y-pass (R5 lesson: acc live across y halves ->
// >128 VGPR -> 1 block/CU -> main loop lost co-residency). Single-pass qsm -> LDS
// [256][136], per-ks att fragments from L2. (512,4) pins <=128 VGPR, 70KB LDS -> 2/CU.
// Softmax without max-subtraction: identical math, |q|<~5 bounded (same as k branch).
__global__ __launch_bounds__(512, 4) void qy_gemm(
    const unsigned short* __restrict__ xn, const unsigned short* __restrict__ wbf,
    const float* __restrict__ bq, const unsigned short* __restrict__ attbf,
    float* __restrict__ out) {
  int m0 = blockIdx.x * 256;
  int h  = blockIdx.y;
  int n0 = h * HDIM;
  int b  = m0 >> 12;
  int bh = b * 8 + h;

  // [0,24576): GEMM staging. Epilogue: [0,34816) qsm [256][136], [34816,35840) reds
  __shared__ __align__(16) unsigned short lds[35840];

  int tid = threadIdx.x;
  int wave = tid >> 6, lane = tid & 63;
  int wr = wave >> 1, wc = wave & 1;
  int wm = wr * 64, wn = wc * 64;
  int l16 = lane & 15, kq = lane >> 4;
  int rs = (kq ^ ((l16 >> 1) & 3)) * 8;

  int arow = tid >> 2;
  int achk = (tid & 3) ^ ((tid >> 3) & 3);
  const unsigned short* Ag = xn + (size_t)(m0 + arow) * DIM + achk * 8;
  const unsigned short* Wg = wbf + (size_t)(n0 + arow) * DIM + achk * 8;

  f32x4 acc[4][4] = {};

  auto stage = [&](int tt, int sb) {
    int kt = tt * 32;
    gld_lds16(Ag + kt,                     lds + sb + wave * 512);
    gld_lds16(Ag + (size_t)128 * DIM + kt, lds + sb + 4096 + wave * 512);
    gld_lds16(Wg + kt,                     lds + sb + 8192 + wave * 512);
  };

  stage(0, 0);
  stage(1, 12288);

  for (int t = 0; t < 32; ++t) {
    int sb = (t & 1) ? 12288 : 0;
    const unsigned short* As = lds + sb;
    const unsigned short* Bs = lds + sb + 8192;

    if (t < 31) asm volatile("s_waitcnt vmcnt(3)" ::: "memory");
    else        asm volatile("s_waitcnt vmcnt(0)" ::: "memory");
    __builtin_amdgcn_sched_barrier(0);
    __builtin_amdgcn_s_barrier();
    __builtin_amdgcn_sched_barrier(0);

    bf16x8 fa[4], fb[4];
#pragma unroll
    for (int i = 0; i < 4; ++i) {
      fa[i] = *(const bf16x8*)(As + (wm + i * 16 + l16) * 32 + rs);
      fb[i] = *(const bf16x8*)(Bs + (wn + i * 16 + l16) * 32 + rs);
    }
#pragma unroll
    for (int i = 0; i < 4; ++i)
#pragma unroll
      for (int j = 0; j < 4; ++j)
        acc[i][j] = __builtin_amdgcn_mfma_f32_16x16x32_bf16(fa[i], fb[j], acc[i][j], 0, 0, 0);

    __builtin_amdgcn_sched_barrier(0);
    __builtin_amdgcn_s_barrier();
    __builtin_amdgcn_sched_barrier(0);
    if (t < 30) stage(t + 2, sb);
    __builtin_amdgcn_sched_barrier(0);
  }

  // bias + exp (no max-sub; single exp per element)
#pragma unroll
  for (int j = 0; j < 4; ++j) {
    float bc = bq[n0 + wn + j * 16 + l16];
#pragma unroll
    for (int i = 0; i < 4; ++i)
#pragma unroll
      for (int r = 0; r < 4; ++r) acc[i][j][r] = __expf(acc[i][j][r] + bc);
  }

  // row sums (head-dim): per-(i,r) sum over j + 16 lanes, combine wc halves via LDS
  float* reds = (float*)(lds + 34816);    // [256][2]
#pragma unroll
  for (int i = 0; i < 4; ++i) {
#pragma unroll
    for (int r = 0; r < 4; ++r) {
      float ps = acc[i][0][r] + acc[i][1][r] + acc[i][2][r] + acc[i][3][r];
      ps += __shfl_xor(ps, 1);
      ps += __shfl_xor(ps, 2);
      ps += __shfl_xor(ps, 4);
      ps += __shfl_xor(ps, 8);
      if (l16 == 0) reds[(wm + i * 16 + kq * 4 + r) * 2 + wc] = ps;
    }
  }
  __syncthreads();

  // normalize + store qsm to LDS [256][136]; acc dies here
#pragma unroll
  for (int i = 0; i < 4; ++i) {
#pragma unroll
    for (int r = 0; r < 4; ++r) {
      int row = wm + i * 16 + kq * 4 + r;
      float inv = 1.0f / (reds[row * 2] + reds[row * 2 + 1]);
#pragma unroll
      for (int j = 0; j < 4; ++j)
        lds[row * 136 + wn + j * 16 + l16] = f2bf(acc[i][j][r] * inv);
    }
  }
  __syncthreads();

  // y-pass: y[256x128] = qsm . att^T; 8 waves tile 4x2 of 64x64
  const unsigned short* attb = attbf + (size_t)bh * 16384;
  f32x4 accy[4][4] = {};
#pragma unroll
  for (int ks = 0; ks < 4; ++ks) {
    bf16x8 fb[4];
#pragma unroll
    for (int jy = 0; jy < 4; ++jy)
      fb[jy] = *(const bf16x8*)(attb + (wn + jy * 16 + l16) * 128 + ks * 32 + kq * 8);
#pragma unroll
    for (int iy = 0; iy < 4; ++iy) {
      bf16x8 fa = *(const bf16x8*)(lds + (wm + iy * 16 + l16) * 136 + ks * 32 + kq * 8);
#pragma unroll
      for (int jy = 0; jy < 4; ++jy)
        accy[iy][jy] = __builtin_amdgcn_mfma_f32_16x16x32_bf16(fa, fb[jy], accy[iy][jy], 0, 0, 0);
    }
  }
#pragma unroll
  for (int jy = 0; jy < 4; ++jy) {
    int colg = n0 + wn + jy * 16 + l16;
#pragma unroll
    for (int iy = 0; iy < 4; ++iy) {
      int rowg = m0 + wm + iy * 16 + kq * 4;
#pragma unroll
      for (int r = 0; r < 4; ++r)
        out[(size_t)(rowg + r) * DIM + colg] = accy[iy][jy][r];
    }
  }
}

extern "C" void kernel_launch(void* const* d_in, const int* in_sizes, int n_in,
                              void* d_out, int out_size, void* d_ws, size_t ws_size,
                              hipStream_t stream) {
  const float* x  = (const float*)d_in[0];
  const float* nw = (const float*)d_in[1];
  const float* nb = (const float*)d_in[2];
  const float* tw = (const float*)d_in[3];
  const float* tb = (const float*)d_in[4];
  const float* Wq = (const float*)d_in[5];
  const float* bq = (const float*)d_in[6];
  const float* Wk = (const float*)d_in[7];
  const float* bk = (const float*)d_in[8];
  const float* Wv = (const float*)d_in[9];
  const float* bv = (const float*)d_in[10];
  float* out = (float*)d_out;

  char* ws = (char*)d_ws;
  unsigned short* xn   = (unsigned short*)(ws);                 // 32 MB (live until qy_gemm)
  unsigned short* xtn  = (unsigned short*)(ws + 33554432);      // 32 MB
  float* slabs         = (float*)(ws + 67108864);               // 32 MB (16 split-K slabs)
  unsigned short* ksmT = (unsigned short*)(ws + 100663296);     // 32 MB  exp(k) transposed
  unsigned short* vT   = (unsigned short*)(ws + 134217728);     // 32 MB  v transposed
  unsigned short* wbf  = (unsigned short*)(ws + 167772160);     // 6 MB
  unsigned short* attbf= (unsigned short*)(ws + 176160768);     // 1 MB
  float* Zk            = (float*)(ws + 177209344);              // 16 KB
  int* cnt             = (int*)(ws + 177225728);                // 128 B

  lnw_kernel<<<ROWS + 3072, 256, 0, stream>>>(x, nw, nb, tw, tb, xn, xtn, Wq, Wk, Wv, wbf, Zk, cnt);
  kv_gemm<<<dim3(64, 8, 2), 512, 0, stream>>>(xtn, wbf, bk, bv, ksmT, vT, Zk);
  att_gemm<<<dim3(16, 32), 256, 0, stream>>>(vT, ksmT, slabs, Zk, attbf, cnt);
  qy_gemm<<<dim3(64, 8), 512, 0, stream>>>(xn, wbf, bq, attbf, out);
}

// Round 7
// 315.862 us; speedup vs baseline: 1.5794x; 1.5794x over previous
//
#include <hip/hip_runtime.h>
#include <cstdint>

#define T_LEN 4096
#define BATCH 4
#define DIM   1024
#define NH    8
#define HDIM  128
#define ROWS  16384   // BATCH * T_LEN

typedef __bf16 bf16x8 __attribute__((ext_vector_type(8)));
typedef float  f32x4  __attribute__((ext_vector_type(4)));

__device__ __forceinline__ unsigned short f2bf(float f) {
  union { float f; unsigned u; } a; a.f = f;
  unsigned u = a.u;
  u += 0x7fff + ((u >> 16) & 1);   // RNE
  return (unsigned short)(u >> 16);
}
__device__ __forceinline__ float bf2f(unsigned short h) {
  union { unsigned u; float f; } a; a.u = ((unsigned)h) << 16;
  return a.f;
}

__device__ __forceinline__ void gld_lds16(const unsigned short* g, unsigned short* l) {
  __builtin_amdgcn_global_load_lds(
      (const __attribute__((address_space(1))) unsigned int*)g,
      (__attribute__((address_space(3))) unsigned int*)l, 16, 0, 0);
}

// ---- LayerNorm (blocks 0..16383) + weight convert (blocks 16384..19455) + Zk zeroing ----
__global__ __launch_bounds__(256) void lnw_kernel(
    const float* __restrict__ x, const float* __restrict__ nw, const float* __restrict__ nb,
    const float* __restrict__ tw, const float* __restrict__ tb,
    unsigned short* __restrict__ xn, unsigned short* __restrict__ xtn,
    const float* __restrict__ Wq, const float* __restrict__ Wk, const float* __restrict__ Wv,
    unsigned short* __restrict__ wbf, float* __restrict__ Zk) {
  int tid = threadIdx.x;
  if (blockIdx.x >= ROWS) {
    int wb = blockIdx.x - ROWS;
    if (wb < 16) Zk[wb * 256 + tid] = 0.0f;           // zero Zk (4096 floats)
    int i4 = wb * 256 + tid;
    int w = i4 >> 18;
    const float* src = (w == 0) ? Wq : (w == 1 ? Wk : Wv);
    float4 v = ((const float4*)src)[i4 & 262143];
    union { unsigned short u[4]; uint2 d; } o;
    o.u[0] = f2bf(v.x); o.u[1] = f2bf(v.y); o.u[2] = f2bf(v.z); o.u[3] = f2bf(v.w);
    ((uint2*)wbf)[i4] = o.d;
    return;
  }
  int row = blockIdx.x;               // t*B + b
  int t = row >> 2, b = row & 3;
  const float4 v = ((const float4*)(x + (size_t)row * DIM))[tid];
  float s  = v.x + v.y + v.z + v.w;
  float s2 = v.x*v.x + v.y*v.y + v.z*v.z + v.w*v.w;
#pragma unroll
  for (int o = 32; o; o >>= 1) { s += __shfl_xor(s, o); s2 += __shfl_xor(s2, o); }
  __shared__ float red[8];
  int wv = tid >> 6;
  if ((tid & 63) == 0) { red[wv] = s; red[4 + wv] = s2; }
  __syncthreads();
  s  = red[0] + red[1] + red[2] + red[3];
  s2 = red[4] + red[5] + red[6] + red[7];
  float mean = s * (1.0f / DIM);
  float var  = s2 * (1.0f / DIM) - mean * mean;
  float rstd = rsqrtf(var + 1e-5f);
  size_t orow = ((size_t)b * T_LEN + t) * DIM;
  int c0 = tid * 4;
  float xv[4] = {v.x, v.y, v.z, v.w};
  union { unsigned short u[4]; uint2 d; } o1, o2;
#pragma unroll
  for (int j = 0; j < 4; ++j) {
    int c = c0 + j;
    float xh = (xv[j] - mean) * rstd;
    o1.u[j] = f2bf(xh * nw[c] + nb[c]);
    o2.u[j] = f2bf(xh * tw[c] + tb[c]);
  }
  *(uint2*)(xn  + orow + c0) = o1.d;
  *(uint2*)(xtn + orow + c0) = o2.d;
}

// ---------------- K/V GEMM: BM=256 BN=128 BK=32, 8 waves, 48KB LDS, (512,4) no-spill ----------------
// zz==1: ksmT[b][c][t] = exp(k + bk) (transposed out) + fused Zk column-sum via atomics
// zz==2: vT[b][c][t]   = v + bv      (transposed out)
__global__ __launch_bounds__(512, 4) void kv_gemm(
    const unsigned short* __restrict__ xtn, const unsigned short* __restrict__ wbf,
    const float* __restrict__ bk, const float* __restrict__ bv,
    unsigned short* __restrict__ ko, unsigned short* __restrict__ vo,
    float* __restrict__ Zk) {
  int zz = blockIdx.z + 1;
  const unsigned short* W = wbf + (size_t)zz * DIM * DIM;
  const float* bias = (zz == 1) ? bk : bv;
  unsigned short* outp = (zz == 1) ? ko : vo;

  int m0 = blockIdx.x * 256;
  int n0 = blockIdx.y * 128;

  __shared__ __align__(16) unsigned short lds[24576];

  int tid = threadIdx.x;
  int wave = tid >> 6, lane = tid & 63;
  int wr = wave >> 1, wc = wave & 1;
  int wm = wr * 64, wn = wc * 64;
  int l16 = lane & 15, kq = lane >> 4;
  int rs = (kq ^ ((l16 >> 1) & 3)) * 8;     // conflict-free read slot (2 lanes/bank)

  int arow = tid >> 2;
  int achk = (tid & 3) ^ ((tid >> 3) & 3);
  const unsigned short* Ag = xtn + (size_t)(m0 + arow) * DIM + achk * 8;
  const unsigned short* Wg = W + (size_t)(n0 + arow) * DIM + achk * 8;

  f32x4 acc[4][4] = {};

  auto stage = [&](int tt, int sb) {
    int kt = tt * 32;
    gld_lds16(Ag + kt,                     lds + sb + wave * 512);
    gld_lds16(Ag + (size_t)128 * DIM + kt, lds + sb + 4096 + wave * 512);
    gld_lds16(Wg + kt,                     lds + sb + 8192 + wave * 512);
  };

  stage(0, 0);
  stage(1, 12288);

  for (int t = 0; t < 32; ++t) {
    int sb = (t & 1) ? 12288 : 0;
    const unsigned short* As = lds + sb;
    const unsigned short* Bs = lds + sb + 8192;

    if (t < 31) asm volatile("s_waitcnt vmcnt(3)" ::: "memory");
    else        asm volatile("s_waitcnt vmcnt(0)" ::: "memory");
    __builtin_amdgcn_sched_barrier(0);
    __builtin_amdgcn_s_barrier();
    __builtin_amdgcn_sched_barrier(0);

    bf16x8 fa[4], fb[4];
#pragma unroll
    for (int i = 0; i < 4; ++i) {
      fa[i] = *(const bf16x8*)(As + (wm + i * 16 + l16) * 32 + rs);
      fb[i] = *(const bf16x8*)(Bs + (wn + i * 16 + l16) * 32 + rs);
    }
#pragma unroll
    for (int i = 0; i < 4; ++i)
#pragma unroll
      for (int j = 0; j < 4; ++j)
        acc[i][j] = __builtin_amdgcn_mfma_f32_16x16x32_bf16(fa[i], fb[j], acc[i][j], 0, 0, 0);

    __builtin_amdgcn_sched_barrier(0);
    __builtin_amdgcn_s_barrier();
    __builtin_amdgcn_sched_barrier(0);
    if (t < 30) stage(t + 2, sb);
    __builtin_amdgcn_sched_barrier(0);
  }

  // bias
#pragma unroll
  for (int j = 0; j < 4; ++j) {
    float bc = bias[n0 + wn + j * 16 + l16];
#pragma unroll
    for (int i = 0; i < 4; ++i)
#pragma unroll
      for (int r = 0; r < 4; ++r) acc[i][j][r] += bc;
  }

  // transposed store: outp[b][col][t]; BM=256 never crosses a batch boundary
  int b = m0 >> 12;
  int tb = m0 & 4095;
  unsigned short* obase = outp + (size_t)b * DIM * T_LEN + tb;
  bool doExp = (zz == 1);
  float zs[4] = {0.0f, 0.0f, 0.0f, 0.0f};
#pragma unroll
  for (int j = 0; j < 4; ++j) {
    int col = n0 + wn + j * 16 + l16;
    unsigned short* cp = obase + (size_t)col * T_LEN;
#pragma unroll
    for (int i = 0; i < 4; ++i) {
      int t0 = wm + i * 16 + kq * 4;
      union { unsigned short u[4]; uint2 d; } o;
#pragma unroll
      for (int r = 0; r < 4; ++r) {
        float val = acc[i][j][r];
        if (doExp) { val = __expf(val); zs[j] += val; }
        o.u[r] = f2bf(val);
      }
      *(uint2*)(cp + t0) = o.d;
    }
  }
  if (doExp) {
#pragma unroll
    for (int j = 0; j < 4; ++j) {
      zs[j] += __shfl_xor(zs[j], 16);
      zs[j] += __shfl_xor(zs[j], 32);
      if (kq == 0) {
        int col = n0 + wn + j * 16 + l16;
        atomicAdd(Zk + b * DIM + col, zs[j]);
      }
    }
  }
}

// ---------------- att GEMM: 16 private split-K slabs, no atomics, no fences ----------------
// slab[kc][bh][l][d] = sum_{t in chunk kc} vT[l][t]*ksmT[d][t]
// (R6 lesson: in-kernel cross-block fence fusion costs L2 writebacks on CDNA4 ->
//  230us idle. The kernel boundary IS the cheap device-wide barrier.)
__global__ __launch_bounds__(256) void att_gemm(
    const unsigned short* __restrict__ vT, const unsigned short* __restrict__ ksmT,
    float* __restrict__ slabs) {
  int kc = blockIdx.x;
  int bh = blockIdx.y;
  const unsigned short* Arow = vT   + (size_t)bh * HDIM * T_LEN;
  const unsigned short* Brow = ksmT + (size_t)bh * HDIM * T_LEN;
  __shared__ __align__(16) unsigned short As[128 * 64];
  __shared__ __align__(16) unsigned short Bs[128 * 64];
  int tid = threadIdx.x;
  int wave = tid >> 6, lane = tid & 63;
  int wm = (wave >> 1) * 64, wn = (wave & 1) * 64;
  int l16 = lane & 15, kq = lane >> 4;
  int swz = l16 & 7;
  int srow = tid >> 3;
  int skk = (((tid & 7) ^ ((tid >> 3) & 7)) * 8);
  const unsigned short* Ag = Arow + (size_t)srow * T_LEN + skk;
  const unsigned short* Bg = Brow + (size_t)srow * T_LEN + skk;
  unsigned short* Al = As + wave * 512;
  unsigned short* Bl = Bs + wave * 512;
  f32x4 acc[4][4] = {};
  int kbeg = kc * 256;
  for (int kt = kbeg; kt < kbeg + 256; kt += 64) {
#pragma unroll
    for (int p = 0; p < 4; ++p) {
      gld_lds16(Ag + (size_t)(p * 32) * T_LEN + kt, Al + p * 2048);
      gld_lds16(Bg + (size_t)(p * 32) * T_LEN + kt, Bl + p * 2048);
    }
    __syncthreads();
#pragma unroll
    for (int ks4 = 0; ks4 < 2; ++ks4) {
      int coff = (((kq + ks4 * 4) ^ swz) * 8);
      bf16x8 fa[4], fb[4];
#pragma unroll
      for (int i = 0; i < 4; ++i) {
        fa[i] = *(const bf16x8*)(As + (wm + i * 16 + l16) * 64 + coff);
        fb[i] = *(const bf16x8*)(Bs + (wn + i * 16 + l16) * 64 + coff);
      }
#pragma unroll
      for (int i = 0; i < 4; ++i)
#pragma unroll
        for (int j = 0; j < 4; ++j)
          acc[i][j] = __builtin_amdgcn_mfma_f32_16x16x32_bf16(fa[i], fb[j], acc[i][j], 0, 0, 0);
    }
    __syncthreads();
  }
  float* op = slabs + ((size_t)kc * 32 + bh) * 16384;
#pragma unroll
  for (int j = 0; j < 4; ++j) {
    int col = wn + j * 16 + l16;
#pragma unroll
    for (int i = 0; i < 4; ++i) {
      int rb = wm + i * 16 + kq * 4;
#pragma unroll
      for (int r = 0; r < 4; ++r)
        op[(size_t)(rb + r) * 128 + col] = acc[i][j][r];
    }
  }
}

// ---------------- att: sum 16 slabs, normalize by Z[d], cast to bf16 ----------------
__global__ __launch_bounds__(256) void attcvt(
    const float* __restrict__ slabs, const float* __restrict__ Zk,
    unsigned short* __restrict__ attbf) {
  int idx = blockIdx.x * 256 + threadIdx.x;
  int bh = idx >> 14;
  int b = bh >> 3, h = bh & 7;
  int d = idx & 127;
  float s = 0.0f;
#pragma unroll
  for (int kc = 0; kc < 16; ++kc) s += slabs[(size_t)kc * 524288 + idx];
  float zv = Zk[b * DIM + h * HDIM + d];
  attbf[idx] = f2bf(s / zv);
}

// ---------------- fused q GEMM + head-dim softmax + y GEMM ----------------
// Epilogue keeps acc DEAD before the y-pass (R5 lesson). Single-pass qsm -> LDS
// [256][136], per-ks att fragments from L2. (512,4) pins <=128 VGPR, 70KB LDS -> 2/CU.
// Softmax without max-subtraction: identical math, |q|<~5 bounded (same as k branch).
__global__ __launch_bounds__(512, 4) void qy_gemm(
    const unsigned short* __restrict__ xn, const unsigned short* __restrict__ wbf,
    const float* __restrict__ bq, const unsigned short* __restrict__ attbf,
    float* __restrict__ out) {
  int m0 = blockIdx.x * 256;
  int h  = blockIdx.y;
  int n0 = h * HDIM;
  int b  = m0 >> 12;
  int bh = b * 8 + h;

  // [0,24576): GEMM staging. Epilogue: [0,34816) qsm [256][136], [34816,35840) reds
  __shared__ __align__(16) unsigned short lds[35840];

  int tid = threadIdx.x;
  int wave = tid >> 6, lane = tid & 63;
  int wr = wave >> 1, wc = wave & 1;
  int wm = wr * 64, wn = wc * 64;
  int l16 = lane & 15, kq = lane >> 4;
  int rs = (kq ^ ((l16 >> 1) & 3)) * 8;

  int arow = tid >> 2;
  int achk = (tid & 3) ^ ((tid >> 3) & 3);
  const unsigned short* Ag = xn + (size_t)(m0 + arow) * DIM + achk * 8;
  const unsigned short* Wg = wbf + (size_t)(n0 + arow) * DIM + achk * 8;

  f32x4 acc[4][4] = {};

  auto stage = [&](int tt, int sb) {
    int kt = tt * 32;
    gld_lds16(Ag + kt,                     lds + sb + wave * 512);
    gld_lds16(Ag + (size_t)128 * DIM + kt, lds + sb + 4096 + wave * 512);
    gld_lds16(Wg + kt,                     lds + sb + 8192 + wave * 512);
  };

  stage(0, 0);
  stage(1, 12288);

  for (int t = 0; t < 32; ++t) {
    int sb = (t & 1) ? 12288 : 0;
    const unsigned short* As = lds + sb;
    const unsigned short* Bs = lds + sb + 8192;

    if (t < 31) asm volatile("s_waitcnt vmcnt(3)" ::: "memory");
    else        asm volatile("s_waitcnt vmcnt(0)" ::: "memory");
    __builtin_amdgcn_sched_barrier(0);
    __builtin_amdgcn_s_barrier();
    __builtin_amdgcn_sched_barrier(0);

    bf16x8 fa[4], fb[4];
#pragma unroll
    for (int i = 0; i < 4; ++i) {
      fa[i] = *(const bf16x8*)(As + (wm + i * 16 + l16) * 32 + rs);
      fb[i] = *(const bf16x8*)(Bs + (wn + i * 16 + l16) * 32 + rs);
    }
#pragma unroll
    for (int i = 0; i < 4; ++i)
#pragma unroll
      for (int j = 0; j < 4; ++j)
        acc[i][j] = __builtin_amdgcn_mfma_f32_16x16x32_bf16(fa[i], fb[j], acc[i][j], 0, 0, 0);

    __builtin_amdgcn_sched_barrier(0);
    __builtin_amdgcn_s_barrier();
    __builtin_amdgcn_sched_barrier(0);
    if (t < 30) stage(t + 2, sb);
    __builtin_amdgcn_sched_barrier(0);
  }

  // bias + exp (no max-sub; single exp per element)
#pragma unroll
  for (int j = 0; j < 4; ++j) {
    float bc = bq[n0 + wn + j * 16 + l16];
#pragma unroll
    for (int i = 0; i < 4; ++i)
#pragma unroll
      for (int r = 0; r < 4; ++r) acc[i][j][r] = __expf(acc[i][j][r] + bc);
  }

  // row sums (head-dim): per-(i,r) sum over j + 16 lanes, combine wc halves via LDS
  float* reds = (float*)(lds + 34816);    // [256][2]
#pragma unroll
  for (int i = 0; i < 4; ++i) {
#pragma unroll
    for (int r = 0; r < 4; ++r) {
      float ps = acc[i][0][r] + acc[i][1][r] + acc[i][2][r] + acc[i][3][r];
      ps += __shfl_xor(ps, 1);
      ps += __shfl_xor(ps, 2);
      ps += __shfl_xor(ps, 4);
      ps += __shfl_xor(ps, 8);
      if (l16 == 0) reds[(wm + i * 16 + kq * 4 + r) * 2 + wc] = ps;
    }
  }
  __syncthreads();

  // normalize + store qsm to LDS [256][136]; acc dies here
#pragma unroll
  for (int i = 0; i < 4; ++i) {
#pragma unroll
    for (int r = 0; r < 4; ++r) {
      int row = wm + i * 16 + kq * 4 + r;
      float inv = 1.0f / (reds[row * 2] + reds[row * 2 + 1]);
#pragma unroll
      for (int j = 0; j < 4; ++j)
        lds[row * 136 + wn + j * 16 + l16] = f2bf(acc[i][j][r] * inv);
    }
  }
  __syncthreads();

  // y-pass: y[256x128] = qsm . att^T; 8 waves tile 4x2 of 64x64
  const unsigned short* attb = attbf + (size_t)bh * 16384;
  f32x4 accy[4][4] = {};
#pragma unroll
  for (int ks = 0; ks < 4; ++ks) {
    bf16x8 fb[4];
#pragma unroll
    for (int jy = 0; jy < 4; ++jy)
      fb[jy] = *(const bf16x8*)(attb + (wn + jy * 16 + l16) * 128 + ks * 32 + kq * 8);
#pragma unroll
    for (int iy = 0; iy < 4; ++iy) {
      bf16x8 fa = *(const bf16x8*)(lds + (wm + iy * 16 + l16) * 136 + ks * 32 + kq * 8);
#pragma unroll
      for (int jy = 0; jy < 4; ++jy)
        accy[iy][jy] = __builtin_amdgcn_mfma_f32_16x16x32_bf16(fa, fb[jy], accy[iy][jy], 0, 0, 0);
    }
  }
#pragma unroll
  for (int jy = 0; jy < 4; ++jy) {
    int colg = n0 + wn + jy * 16 + l16;
#pragma unroll
    for (int iy = 0; iy < 4; ++iy) {
      int rowg = m0 + wm + iy * 16 + kq * 4;
#pragma unroll
      for (int r = 0; r < 4; ++r)
        out[(size_t)(rowg + r) * DIM + colg] = accy[iy][jy][r];
    }
  }
}

extern "C" void kernel_launch(void* const* d_in, const int* in_sizes, int n_in,
                              void* d_out, int out_size, void* d_ws, size_t ws_size,
                              hipStream_t stream) {
  const float* x  = (const float*)d_in[0];
  const float* nw = (const float*)d_in[1];
  const float* nb = (const float*)d_in[2];
  const float* tw = (const float*)d_in[3];
  const float* tb = (const float*)d_in[4];
  const float* Wq = (const float*)d_in[5];
  const float* bq = (const float*)d_in[6];
  const float* Wk = (const float*)d_in[7];
  const float* bk = (const float*)d_in[8];
  const float* Wv = (const float*)d_in[9];
  const float* bv = (const float*)d_in[10];
  float* out = (float*)d_out;

  char* ws = (char*)d_ws;
  unsigned short* xn   = (unsigned short*)(ws);                 // 32 MB (live until qy_gemm)
  unsigned short* xtn  = (unsigned short*)(ws + 33554432);      // 32 MB
  float* slabs         = (float*)(ws + 67108864);               // 32 MB (16 split-K slabs)
  unsigned short* ksmT = (unsigned short*)(ws + 100663296);     // 32 MB  exp(k) transposed
  unsigned short* vT   = (unsigned short*)(ws + 134217728);     // 32 MB  v transposed
  unsigned short* wbf  = (unsigned short*)(ws + 167772160);     // 6 MB
  unsigned short* attbf= (unsigned short*)(ws + 176160768);     // 1 MB
  float* Zk            = (float*)(ws + 177209344);              // 16 KB

  lnw_kernel<<<ROWS + 3072, 256, 0, stream>>>(x, nw, nb, tw, tb, xn, xtn, Wq, Wk, Wv, wbf, Zk);
  kv_gemm<<<dim3(64, 8, 2), 512, 0, stream>>>(xtn, wbf, bk, bv, ksmT, vT, Zk);
  att_gemm<<<dim3(16, 32), 256, 0, stream>>>(vT, ksmT, slabs);
  attcvt<<<2048, 256, 0, stream>>>(slabs, Zk, attbf);
  qy_gemm<<<dim3(64, 8), 512, 0, stream>>>(xn, wbf, bq, attbf, out);
}